// Round 9
// baseline (387.964 us; speedup 1.0000x reference)
//
#include <hip/hip_runtime.h>
#include <math.h>

#define B_DIM 8
#define S_DIM 4096
#define D_DIM 1024
#define N_DIM 16
#define ROWS (B_DIM * S_DIM)          // 32768

#define CHUNK_L 32
#define WARM 64
#define STEPS (CHUNK_L + WARM)        // 96 sequential steps per chain
#define NCHAIN (B_DIM * (S_DIM / CHUNK_L))   // 1024 chains

#define KSPLIT 16
#define KB 64                         // k per block
#define RT2 512                       // rows per block (64 rg x 8)
#define XB2_BLOCKS ((ROWS / RT2) * KSPLIT)   // 64 * 16 = 1024
#define CW_BLOCKS ((N_DIM * D_DIM) / 256)    // 64

// ---------------------------------------------------------------------------
// Kernel 1 (fused):
//  blocks [0, XB2_BLOCKS): partial xb GEMM. Thread owns 8 rows x 4 n.
//  Per k-quad per wave: 4 ds_read_b128 (B) = 48 DS cy vs 256 VALU cy of FMA
//  -> per CU (4 waves): DS 192 < VALU 256 => VALU/HBM-bound by construction.
//  x read DIRECTLY from global (TA pipe; 64B lines reused across 4 k-quads
//  via L1). K-split 16 => 1024 blocks = 4 blocks/CU = 4 waves/SIMD for
//  latency hiding + explicit depth-2 register ping-pong (~400 cy lead).
//  B-chunk (64x16 = 4KB) staged to LDS once. No x re-read across splits.
//  blocks [XB2_BLOCKS, +CW_BLOCKS): CW[n][d] = sum_k C[n][k]*W[d][k].
// ---------------------------------------------------------------------------
__global__ __launch_bounds__(256, 4) void k_xbcw(const float* __restrict__ x,
                                                 const float* __restrict__ Bm,
                                                 float* __restrict__ parts,
                                                 const float* __restrict__ C,
                                                 const float* __restrict__ W,
                                                 float* __restrict__ CW) {
    const int t = threadIdx.x;
    if (blockIdx.x >= XB2_BLOCKS) {
        // ---- CW part (round-1 proven) ----
        int u = (blockIdx.x - XB2_BLOCKS) * 256 + t;
        int d = u >> 4;
        int n = u & 15;
        const float* crow = C + n * D_DIM;
        const float* wrow = W + (size_t)d * D_DIM;
        float acc = 0.f;
#pragma unroll 4
        for (int k = 0; k < D_DIM; k += 4) {
            float4 c4 = *(const float4*)(crow + k);
            float4 w4 = *(const float4*)(wrow + k);
            acc = fmaf(c4.x, w4.x, acc);
            acc = fmaf(c4.y, w4.y, acc);
            acc = fmaf(c4.z, w4.z, acc);
            acc = fmaf(c4.w, w4.w, acc);
        }
        CW[n * D_DIM + d] = acc;
        return;
    }
    // ---- xb partial ----
    __shared__ float bs[KB * N_DIM];           // 4 KB, linear [k][n]
    const int rt = blockIdx.x >> 4;            // row tile 0..63
    const int ks = blockIdx.x & 15;            // k-split 0..15
    const int row0 = rt * RT2;
    const int k0 = ks * KB;

    // stage B chunk: 256 float4, 1 per thread, coalesced
    *(float4*)(bs + t * 4) = *(const float4*)(Bm + (size_t)k0 * N_DIM + t * 4);
    __syncthreads();

    const int rg = t >> 2;                     // row group 0..63 (8 rows each)
    const int nq = (t & 3) * 4;                // n quad
    const float* xr = x + (size_t)(row0 + rg * 8) * D_DIM + k0;

    float4 acc[8];
#pragma unroll
    for (int i = 0; i < 8; ++i) acc[i] = {0.f, 0.f, 0.f, 0.f};

    float4 bufA[8], bufB[8];
#pragma unroll
    for (int i = 0; i < 8; ++i)
        bufA[i] = *(const float4*)(xr + (size_t)i * D_DIM);
#pragma unroll
    for (int i = 0; i < 8; ++i)
        bufB[i] = *(const float4*)(xr + (size_t)i * D_DIM + 4);

#define FMAALL(BUF, JJ)                                                    \
    {                                                                      \
        const float* bk = bs + (JJ) * 4 * N_DIM + nq;                      \
        float4 b0 = *(const float4*)(bk + 0 * N_DIM);                      \
        float4 b1 = *(const float4*)(bk + 1 * N_DIM);                      \
        float4 b2 = *(const float4*)(bk + 2 * N_DIM);                      \
        float4 b3 = *(const float4*)(bk + 3 * N_DIM);                      \
        _Pragma("unroll")                                                  \
        for (int i = 0; i < 8; ++i) {                                      \
            float4 xv = BUF[i];                                            \
            float4 a = acc[i];                                             \
            a.x = fmaf(xv.x, b0.x, a.x); a.y = fmaf(xv.x, b0.y, a.y);      \
            a.z = fmaf(xv.x, b0.z, a.z); a.w = fmaf(xv.x, b0.w, a.w);      \
            a.x = fmaf(xv.y, b1.x, a.x); a.y = fmaf(xv.y, b1.y, a.y);      \
            a.z = fmaf(xv.y, b1.z, a.z); a.w = fmaf(xv.y, b1.w, a.w);      \
            a.x = fmaf(xv.z, b2.x, a.x); a.y = fmaf(xv.z, b2.y, a.y);      \
            a.z = fmaf(xv.z, b2.z, a.z); a.w = fmaf(xv.z, b2.w, a.w);      \
            a.x = fmaf(xv.w, b3.x, a.x); a.y = fmaf(xv.w, b3.y, a.y);      \
            a.z = fmaf(xv.w, b3.z, a.z); a.w = fmaf(xv.w, b3.w, a.w);      \
            acc[i] = a;                                                    \
        }                                                                  \
    }

    for (int j = 0; j < 16; j += 2) {
        FMAALL(bufA, j)
        if (j + 2 < 16) {
#pragma unroll
            for (int i = 0; i < 8; ++i)
                bufA[i] = *(const float4*)(xr + (size_t)i * D_DIM + (j + 2) * 4);
        }
        FMAALL(bufB, j + 1)
        if (j + 3 < 16) {
#pragma unroll
            for (int i = 0; i < 8; ++i)
                bufB[i] = *(const float4*)(xr + (size_t)i * D_DIM + (j + 3) * 4);
        }
    }
#undef FMAALL

    float* op = parts + ((size_t)ks * ROWS + row0 + rg * 8) * N_DIM + nq;
#pragma unroll
    for (int i = 0; i < 8; ++i)
        *(float4*)(op + (size_t)i * N_DIM) = acc[i];
}

// ---------------------------------------------------------------------------
// Kernel 1b: xb = sum of 16 k-split partials (sequential order, determ.)
// ---------------------------------------------------------------------------
__global__ __launch_bounds__(256) void k_red(const float* __restrict__ parts,
                                             float* __restrict__ xb) {
    int i = (blockIdx.x * 256 + threadIdx.x) * 4;
    const size_t Q = (size_t)ROWS * N_DIM;
    float4 s = *(const float4*)(parts + i);
#pragma unroll
    for (int q = 1; q < KSPLIT; ++q) {
        float4 v = *(const float4*)(parts + (size_t)q * Q + i);
        s.x += v.x; s.y += v.y; s.z += v.z; s.w += v.w;
    }
    *(float4*)(xb + i) = s;
}

// ---------------------------------------------------------------------------
// Kernel 2: chunked scan (round-6 proven, UNCHANGED)
// ---------------------------------------------------------------------------
__global__ __launch_bounds__(64) void k_scan(const float* __restrict__ xb,
                                             const float* __restrict__ A,
                                             float* __restrict__ hs) {
    const int tid = threadIdx.x;           // 0..63
    const int n = tid & 15;
    const int base4 = (tid & 48) * 4;

    const int chain = blockIdx.x * 4 + (tid >> 4);   // 0..1023
    const int b = chain >> 7;
    const int chunk = chain & 127;
    const int t0 = chunk * CHUNK_L - WARM;

    float Ar[16];
#pragma unroll
    for (int m4 = 0; m4 < 16; m4 += 4) {
        float4 v = *(const float4*)(A + n * 16 + m4);
        Ar[m4 + 0] = v.x; Ar[m4 + 1] = v.y; Ar[m4 + 2] = v.z; Ar[m4 + 3] = v.w;
    }

    const float* xp = xb + (size_t)b * S_DIM * N_DIM + n;
    float* hp = hs + (size_t)b * S_DIM * N_DIM + n;

    float ring[8];
#pragma unroll
    for (int i = 0; i < 8; ++i) {
        int tt = t0 + i;
        ring[i] = (tt >= 0) ? xp[(size_t)tt * N_DIM] : 0.f;
    }

    float h = 0.f;
    for (int tr0 = 0; tr0 < STEPS; tr0 += 8) {
#pragma unroll
        for (int j = 0; j < 8; ++j) {
            const int tr = tr0 + j;
            const float xv = ring[j];
            const int hbits = __float_as_int(h);
            int hm[16];
#pragma unroll
            for (int m = 0; m < 16; ++m)
                hm[m] = __builtin_amdgcn_ds_bpermute(base4 + m * 4, hbits);
            float acc0 = xv, acc1 = 0.f;
#pragma unroll
            for (int m = 0; m < 8; ++m) {
                acc0 = fmaf(Ar[m], __int_as_float(hm[m]), acc0);
                acc1 = fmaf(Ar[m + 8], __int_as_float(hm[m + 8]), acc1);
            }
            float g = acc0 + acc1;
            float ax = fabsf(g);
            float e = __expf(2.f * ax);
            float tv = 1.f - 2.f / (e + 1.f);
            h = (g < 0.f) ? -tv : tv;
            if (tr >= WARM)
                hp[(size_t)(t0 + tr) * N_DIM] = h;
            int tt = t0 + tr + 8;
            if (tr + 8 < STEPS)
                ring[j] = (tt >= 0) ? xp[(size_t)tt * N_DIM] : 0.f;
        }
    }
}

// ---------------------------------------------------------------------------
// Kernel 3: out[r][d] = sum_n hs[r][n] * CW[n][d] + bias[d]  (round-1 proven)
// ---------------------------------------------------------------------------
__global__ __launch_bounds__(256) void k_out(const float* __restrict__ hs,
                                             const float* __restrict__ CW,
                                             const float* __restrict__ bias,
                                             float* __restrict__ out) {
    const int t = threadIdx.x;
    const int d0 = t * 4;
    const int row0 = blockIdx.x * 32;
    float4 cw[16];
#pragma unroll
    for (int nn = 0; nn < 16; ++nn)
        cw[nn] = *(const float4*)(CW + nn * D_DIM + d0);
    float4 b4 = *(const float4*)(bias + d0);

    for (int r = row0; r < row0 + 32; ++r) {
        const float4* hp = (const float4*)(hs + (size_t)r * N_DIM);
        float4 h0 = hp[0], h1 = hp[1], h2 = hp[2], h3 = hp[3];
        float hv[16] = {h0.x, h0.y, h0.z, h0.w, h1.x, h1.y, h1.z, h1.w,
                        h2.x, h2.y, h2.z, h2.w, h3.x, h3.y, h3.z, h3.w};
        float4 acc = b4;
#pragma unroll
        for (int nn = 0; nn < 16; ++nn) {
            acc.x = fmaf(hv[nn], cw[nn].x, acc.x);
            acc.y = fmaf(hv[nn], cw[nn].y, acc.y);
            acc.z = fmaf(hv[nn], cw[nn].z, acc.z);
            acc.w = fmaf(hv[nn], cw[nn].w, acc.w);
        }
        *(float4*)(out + (size_t)r * D_DIM + d0) = acc;
    }
}

// ---------------------------------------------------------------------------
extern "C" void kernel_launch(void* const* d_in, const int* in_sizes, int n_in,
                              void* d_out, int out_size, void* d_ws,
                              size_t ws_size, hipStream_t stream) {
    const float* x    = (const float*)d_in[0];   // [8,4096,1024]
    const float* A    = (const float*)d_in[1];   // [16,16]
    const float* Bm   = (const float*)d_in[2];   // [1024,16]
    const float* C    = (const float*)d_in[3];   // [16,1024]
    const float* W    = (const float*)d_in[4];   // [1024,1024]
    const float* bias = (const float*)d_in[5];   // [1024]
    float* out = (float*)d_out;

    float* ws    = (float*)d_ws;
    float* xb    = ws;                           // 524288 floats
    float* hs    = ws + 524288;                  // 524288
    float* CW    = ws + 1048576;                 // 16384
    float* parts = ws + 1064960;                 // 16 * 524288 floats

    k_xbcw<<<dim3(XB2_BLOCKS + CW_BLOCKS), dim3(256), 0, stream>>>(
        x, Bm, parts, C, W, CW);
    k_red<<<dim3(ROWS * N_DIM / 1024), dim3(256), 0, stream>>>(parts, xb);
    k_scan<<<dim3(NCHAIN / 4), dim3(64), 0, stream>>>(xb, A, hs);
    k_out<<<dim3(ROWS / 32), dim3(256), 0, stream>>>(hs, CW, bias, out);
}

// Round 10
// 177.714 us; speedup vs baseline: 2.1831x; 2.1831x over previous
//
#include <hip/hip_runtime.h>
#include <math.h>

#define B_DIM 8
#define S_DIM 4096
#define D_DIM 1024
#define N_DIM 16
#define ROWS (B_DIM * S_DIM)          // 32768

#define CHUNK_L 32
#define WARM 64
#define STEPS (CHUNK_L + WARM)        // 96 sequential steps per chain
#define NCHAIN (B_DIM * (S_DIM / CHUNK_L))   // 1024 chains

#define KSPLIT 8
#define KB_K 128                      // k per block
#define XRT 256                       // rows per block
#define XB_BLOCKS ((ROWS / XRT) * KSPLIT)    // 128 * 8 = 1024
#define CW_BLOCKS ((N_DIM * D_DIM) / 256)    // 64

// ---------------------------------------------------------------------------
// Kernel 1 (fused):
//  blocks [0, XB_BLOCKS): partial xb GEMM. Thread owns 4 rows x 4 n.
//  Per 16-k chunk: issue ALL 4 float4 of each row's 64B line back-to-back
//  (16 loads; line fully consumed in one batch -> FETCH == x size exactly,
//  no L1 reliance — fixes R9's 4.6x over-fetch). Then 4 FMA quads vs B from
//  LDS: per wave per quad 4 ds_read_b128 (48 cy) vs 128 VALU cy -> DS ~40%
//  of VALU; per-CU DS ~10us < HBM ~21us. K-split 8 -> 1024 blocks = 4/CU =
//  16 waves/CU for latency TLP (launch_bounds(256,4), ~100 VGPR).
//  blocks [XB_BLOCKS, +CW_BLOCKS): CW[n][d] = sum_k C[n][k]*W[d][k].
// ---------------------------------------------------------------------------
__global__ __launch_bounds__(256, 4) void k_xbcw(const float* __restrict__ x,
                                                 const float* __restrict__ Bm,
                                                 float* __restrict__ parts,
                                                 const float* __restrict__ C,
                                                 const float* __restrict__ W,
                                                 float* __restrict__ CW) {
    const int t = threadIdx.x;
    if (blockIdx.x >= XB_BLOCKS) {
        // ---- CW part (round-1 proven) ----
        int u = (blockIdx.x - XB_BLOCKS) * 256 + t;
        int d = u >> 4;
        int n = u & 15;
        const float* crow = C + n * D_DIM;
        const float* wrow = W + (size_t)d * D_DIM;
        float acc = 0.f;
#pragma unroll 4
        for (int k = 0; k < D_DIM; k += 4) {
            float4 c4 = *(const float4*)(crow + k);
            float4 w4 = *(const float4*)(wrow + k);
            acc = fmaf(c4.x, w4.x, acc);
            acc = fmaf(c4.y, w4.y, acc);
            acc = fmaf(c4.z, w4.z, acc);
            acc = fmaf(c4.w, w4.w, acc);
        }
        CW[n * D_DIM + d] = acc;
        return;
    }
    // ---- xb partial ----
    __shared__ float bs[KB_K * N_DIM];         // 8 KB, linear [k][n]
    const int rt = blockIdx.x >> 3;            // row tile 0..127
    const int ks = blockIdx.x & 7;             // k-split 0..7
    const int row0 = rt * XRT;
    const int k0 = ks * KB_K;

    // stage B chunk: 512 float4, 2 per thread, coalesced
#pragma unroll
    for (int p = 0; p < 2; ++p) {
        int fid = p * 256 + t;
        *(float4*)(bs + fid * 4) =
            *(const float4*)(Bm + (size_t)k0 * N_DIM + fid * 4);
    }
    __syncthreads();

    const int rg = t >> 2;                     // row group 0..63 (4 rows)
    const int nq = (t & 3) * 4;                // n quad
    const float* xr = x + (size_t)(row0 + rg * 4) * D_DIM + k0;

    float4 acc[4];
#pragma unroll
    for (int i = 0; i < 4; ++i) acc[i] = {0.f, 0.f, 0.f, 0.f};

    for (int c = 0; c < KB_K / 16; ++c) {      // 8 chunks of 16 k
        // load batch: full 64B line per row, all 4 rows, back-to-back
        float4 buf[16];
#pragma unroll
        for (int i = 0; i < 4; ++i)
#pragma unroll
            for (int q = 0; q < 4; ++q)
                buf[i * 4 + q] = *(const float4*)(xr + (size_t)i * D_DIM +
                                                  c * 16 + q * 4);
        // compute: 4 quads; B rows from LDS (broadcast b128, conflict-free)
#pragma unroll
        for (int q = 0; q < 4; ++q) {
            const float* bk = bs + (c * 16 + q * 4) * N_DIM + nq;
            float4 b0 = *(const float4*)(bk + 0 * N_DIM);
            float4 b1 = *(const float4*)(bk + 1 * N_DIM);
            float4 b2 = *(const float4*)(bk + 2 * N_DIM);
            float4 b3 = *(const float4*)(bk + 3 * N_DIM);
#pragma unroll
            for (int i = 0; i < 4; ++i) {
                float4 xv = buf[i * 4 + q];
                float4 a = acc[i];
                a.x = fmaf(xv.x, b0.x, a.x); a.y = fmaf(xv.x, b0.y, a.y);
                a.z = fmaf(xv.x, b0.z, a.z); a.w = fmaf(xv.x, b0.w, a.w);
                a.x = fmaf(xv.y, b1.x, a.x); a.y = fmaf(xv.y, b1.y, a.y);
                a.z = fmaf(xv.y, b1.z, a.z); a.w = fmaf(xv.y, b1.w, a.w);
                a.x = fmaf(xv.z, b2.x, a.x); a.y = fmaf(xv.z, b2.y, a.y);
                a.z = fmaf(xv.z, b2.z, a.z); a.w = fmaf(xv.z, b2.w, a.w);
                a.x = fmaf(xv.w, b3.x, a.x); a.y = fmaf(xv.w, b3.y, a.y);
                a.z = fmaf(xv.w, b3.z, a.z); a.w = fmaf(xv.w, b3.w, a.w);
                acc[i] = a;
            }
        }
    }

    float* op = parts + ((size_t)ks * ROWS + row0 + rg * 4) * N_DIM + nq;
#pragma unroll
    for (int i = 0; i < 4; ++i)
        *(float4*)(op + (size_t)i * N_DIM) = acc[i];
}

// ---------------------------------------------------------------------------
// Kernel 1b: xb = sum of 8 k-split partials (sequential order, determ.)
// ---------------------------------------------------------------------------
__global__ __launch_bounds__(256) void k_red(const float* __restrict__ parts,
                                             float* __restrict__ xb) {
    int i = (blockIdx.x * 256 + threadIdx.x) * 4;
    const size_t Q = (size_t)ROWS * N_DIM;
    float4 s = *(const float4*)(parts + i);
#pragma unroll
    for (int q = 1; q < KSPLIT; ++q) {
        float4 v = *(const float4*)(parts + (size_t)q * Q + i);
        s.x += v.x; s.y += v.y; s.z += v.z; s.w += v.w;
    }
    *(float4*)(xb + i) = s;
}

// ---------------------------------------------------------------------------
// Kernel 2: chunked scan (round-6 proven, UNCHANGED)
// ---------------------------------------------------------------------------
__global__ __launch_bounds__(64) void k_scan(const float* __restrict__ xb,
                                             const float* __restrict__ A,
                                             float* __restrict__ hs) {
    const int tid = threadIdx.x;           // 0..63
    const int n = tid & 15;
    const int base4 = (tid & 48) * 4;

    const int chain = blockIdx.x * 4 + (tid >> 4);   // 0..1023
    const int b = chain >> 7;
    const int chunk = chain & 127;
    const int t0 = chunk * CHUNK_L - WARM;

    float Ar[16];
#pragma unroll
    for (int m4 = 0; m4 < 16; m4 += 4) {
        float4 v = *(const float4*)(A + n * 16 + m4);
        Ar[m4 + 0] = v.x; Ar[m4 + 1] = v.y; Ar[m4 + 2] = v.z; Ar[m4 + 3] = v.w;
    }

    const float* xp = xb + (size_t)b * S_DIM * N_DIM + n;
    float* hp = hs + (size_t)b * S_DIM * N_DIM + n;

    float ring[8];
#pragma unroll
    for (int i = 0; i < 8; ++i) {
        int tt = t0 + i;
        ring[i] = (tt >= 0) ? xp[(size_t)tt * N_DIM] : 0.f;
    }

    float h = 0.f;
    for (int tr0 = 0; tr0 < STEPS; tr0 += 8) {
#pragma unroll
        for (int j = 0; j < 8; ++j) {
            const int tr = tr0 + j;
            const float xv = ring[j];
            const int hbits = __float_as_int(h);
            int hm[16];
#pragma unroll
            for (int m = 0; m < 16; ++m)
                hm[m] = __builtin_amdgcn_ds_bpermute(base4 + m * 4, hbits);
            float acc0 = xv, acc1 = 0.f;
#pragma unroll
            for (int m = 0; m < 8; ++m) {
                acc0 = fmaf(Ar[m], __int_as_float(hm[m]), acc0);
                acc1 = fmaf(Ar[m + 8], __int_as_float(hm[m + 8]), acc1);
            }
            float g = acc0 + acc1;
            float ax = fabsf(g);
            float e = __expf(2.f * ax);
            float tv = 1.f - 2.f / (e + 1.f);
            h = (g < 0.f) ? -tv : tv;
            if (tr >= WARM)
                hp[(size_t)(t0 + tr) * N_DIM] = h;
            int tt = t0 + tr + 8;
            if (tr + 8 < STEPS)
                ring[j] = (tt >= 0) ? xp[(size_t)tt * N_DIM] : 0.f;
        }
    }
}

// ---------------------------------------------------------------------------
// Kernel 3: out[r][d] = sum_n hs[r][n] * CW[n][d] + bias[d]  (round-1 proven)
// ---------------------------------------------------------------------------
__global__ __launch_bounds__(256) void k_out(const float* __restrict__ hs,
                                             const float* __restrict__ CW,
                                             const float* __restrict__ bias,
                                             float* __restrict__ out) {
    const int t = threadIdx.x;
    const int d0 = t * 4;
    const int row0 = blockIdx.x * 32;
    float4 cw[16];
#pragma unroll
    for (int nn = 0; nn < 16; ++nn)
        cw[nn] = *(const float4*)(CW + nn * D_DIM + d0);
    float4 b4 = *(const float4*)(bias + d0);

    for (int r = row0; r < row0 + 32; ++r) {
        const float4* hp = (const float4*)(hs + (size_t)r * N_DIM);
        float4 h0 = hp[0], h1 = hp[1], h2 = hp[2], h3 = hp[3];
        float hv[16] = {h0.x, h0.y, h0.z, h0.w, h1.x, h1.y, h1.z, h1.w,
                        h2.x, h2.y, h2.z, h2.w, h3.x, h3.y, h3.z, h3.w};
        float4 acc = b4;
#pragma unroll
        for (int nn = 0; nn < 16; ++nn) {
            acc.x = fmaf(hv[nn], cw[nn].x, acc.x);
            acc.y = fmaf(hv[nn], cw[nn].y, acc.y);
            acc.z = fmaf(hv[nn], cw[nn].z, acc.z);
            acc.w = fmaf(hv[nn], cw[nn].w, acc.w);
        }
        *(float4*)(out + (size_t)r * D_DIM + d0) = acc;
    }
}

// ---------------------------------------------------------------------------
extern "C" void kernel_launch(void* const* d_in, const int* in_sizes, int n_in,
                              void* d_out, int out_size, void* d_ws,
                              size_t ws_size, hipStream_t stream) {
    const float* x    = (const float*)d_in[0];   // [8,4096,1024]
    const float* A    = (const float*)d_in[1];   // [16,16]
    const float* Bm   = (const float*)d_in[2];   // [1024,16]
    const float* C    = (const float*)d_in[3];   // [16,1024]
    const float* W    = (const float*)d_in[4];   // [1024,1024]
    const float* bias = (const float*)d_in[5];   // [1024]
    float* out = (float*)d_out;

    float* ws    = (float*)d_ws;
    float* xb    = ws;                           // 524288 floats
    float* hs    = ws + 524288;                  // 524288
    float* CW    = ws + 1048576;                 // 16384
    float* parts = ws + 1064960;                 // 8 * 524288 floats

    k_xbcw<<<dim3(XB_BLOCKS + CW_BLOCKS), dim3(256), 0, stream>>>(
        x, Bm, parts, C, W, CW);
    k_red<<<dim3(ROWS * N_DIM / 1024), dim3(256), 0, stream>>>(parts, xb);
    k_scan<<<dim3(NCHAIN / 4), dim3(64), 0, stream>>>(xb, A, hs);
    k_out<<<dim3(ROWS / 32), dim3(256), 0, stream>>>(hs, CW, bias, out);
}

// Round 11
// 173.019 us; speedup vs baseline: 2.2423x; 1.0271x over previous
//
#include <hip/hip_runtime.h>
#include <math.h>

#define B_DIM 8
#define S_DIM 4096
#define D_DIM 1024
#define N_DIM 16
#define ROWS (B_DIM * S_DIM)          // 32768

#define CHUNK_L 32
#define WARM 64
#define STEPS (CHUNK_L + WARM)        // 96 sequential steps per chain
#define NCHAIN (B_DIM * (S_DIM / CHUNK_L))   // 1024 chains

#define KSPLIT 16
#define KB_K 64                       // k per block
#define XRT 256                       // rows per block
#define XB_BLOCKS ((ROWS / XRT) * KSPLIT)    // 128 * 16 = 2048
#define CW_BLOCKS ((N_DIM * D_DIM) / 256)    // 64

// ---------------------------------------------------------------------------
// Kernel 1 (fused):
//  blocks [0, XB_BLOCKS): partial xb GEMM. Thread owns 4 rows x 4 n, 64 k.
//  Per 16-k chunk: all 4 float4 of each row's 64B line issued back-to-back
//  (line fully consumed -> FETCH == x size, proven in R10). KSPLIT 16 ->
//  grid 2048 = 8 blocks/CU = 32 waves/CU (VGPR 36, LDS 4KB both fit):
//  TLP covers the ~900cy HBM latency that R10's 4-blocks/CU couldn't.
//  blocks [XB_BLOCKS, +CW_BLOCKS): CW[n][d] = sum_k C[n][k]*W[d][k].
// ---------------------------------------------------------------------------
__global__ __launch_bounds__(256) void k_xbcw(const float* __restrict__ x,
                                              const float* __restrict__ Bm,
                                              float* __restrict__ parts,
                                              const float* __restrict__ C,
                                              const float* __restrict__ W,
                                              float* __restrict__ CW) {
    const int t = threadIdx.x;
    if (blockIdx.x >= XB_BLOCKS) {
        // ---- CW part (round-1 proven) ----
        int u = (blockIdx.x - XB_BLOCKS) * 256 + t;
        int d = u >> 4;
        int n = u & 15;
        const float* crow = C + n * D_DIM;
        const float* wrow = W + (size_t)d * D_DIM;
        float acc = 0.f;
#pragma unroll 4
        for (int k = 0; k < D_DIM; k += 4) {
            float4 c4 = *(const float4*)(crow + k);
            float4 w4 = *(const float4*)(wrow + k);
            acc = fmaf(c4.x, w4.x, acc);
            acc = fmaf(c4.y, w4.y, acc);
            acc = fmaf(c4.z, w4.z, acc);
            acc = fmaf(c4.w, w4.w, acc);
        }
        CW[n * D_DIM + d] = acc;
        return;
    }
    // ---- xb partial ----
    __shared__ float bs[KB_K * N_DIM];         // 4 KB, linear [k][n]
    const int rt = blockIdx.x >> 4;            // row tile 0..127
    const int ks = blockIdx.x & 15;            // k-split 0..15
    const int row0 = rt * XRT;
    const int k0 = ks * KB_K;

    // stage B chunk: 256 float4, 1 per thread, coalesced
    *(float4*)(bs + t * 4) = *(const float4*)(Bm + (size_t)k0 * N_DIM + t * 4);
    __syncthreads();

    const int rg = t >> 2;                     // row group 0..63 (4 rows)
    const int nq = (t & 3) * 4;                // n quad
    const float* xr = x + (size_t)(row0 + rg * 4) * D_DIM + k0;

    float4 acc[4];
#pragma unroll
    for (int i = 0; i < 4; ++i) acc[i] = {0.f, 0.f, 0.f, 0.f};

    for (int c = 0; c < KB_K / 16; ++c) {      // 4 chunks of 16 k
        // load batch: full 64B line per row, all 4 rows, back-to-back
        float4 buf[16];
#pragma unroll
        for (int i = 0; i < 4; ++i)
#pragma unroll
            for (int q = 0; q < 4; ++q)
                buf[i * 4 + q] = *(const float4*)(xr + (size_t)i * D_DIM +
                                                  c * 16 + q * 4);
        // compute: 4 quads; B rows from LDS (broadcast b128, conflict-free)
#pragma unroll
        for (int q = 0; q < 4; ++q) {
            const float* bk = bs + (c * 16 + q * 4) * N_DIM + nq;
            float4 b0 = *(const float4*)(bk + 0 * N_DIM);
            float4 b1 = *(const float4*)(bk + 1 * N_DIM);
            float4 b2 = *(const float4*)(bk + 2 * N_DIM);
            float4 b3 = *(const float4*)(bk + 3 * N_DIM);
#pragma unroll
            for (int i = 0; i < 4; ++i) {
                float4 xv = buf[i * 4 + q];
                float4 a = acc[i];
                a.x = fmaf(xv.x, b0.x, a.x); a.y = fmaf(xv.x, b0.y, a.y);
                a.z = fmaf(xv.x, b0.z, a.z); a.w = fmaf(xv.x, b0.w, a.w);
                a.x = fmaf(xv.y, b1.x, a.x); a.y = fmaf(xv.y, b1.y, a.y);
                a.z = fmaf(xv.y, b1.z, a.z); a.w = fmaf(xv.y, b1.w, a.w);
                a.x = fmaf(xv.z, b2.x, a.x); a.y = fmaf(xv.z, b2.y, a.y);
                a.z = fmaf(xv.z, b2.z, a.z); a.w = fmaf(xv.z, b2.w, a.w);
                a.x = fmaf(xv.w, b3.x, a.x); a.y = fmaf(xv.w, b3.y, a.y);
                a.z = fmaf(xv.w, b3.z, a.z); a.w = fmaf(xv.w, b3.w, a.w);
                acc[i] = a;
            }
        }
    }

    float* op = parts + ((size_t)ks * ROWS + row0 + rg * 4) * N_DIM + nq;
#pragma unroll
    for (int i = 0; i < 4; ++i)
        *(float4*)(op + (size_t)i * N_DIM) = acc[i];
}

// ---------------------------------------------------------------------------
// Kernel 1b: xb = sum of 16 k-split partials (sequential order, determ.)
// ---------------------------------------------------------------------------
__global__ __launch_bounds__(256) void k_red(const float* __restrict__ parts,
                                             float* __restrict__ xb) {
    int i = (blockIdx.x * 256 + threadIdx.x) * 4;
    const size_t Q = (size_t)ROWS * N_DIM;
    float4 s = *(const float4*)(parts + i);
#pragma unroll
    for (int q = 1; q < KSPLIT; ++q) {
        float4 v = *(const float4*)(parts + (size_t)q * Q + i);
        s.x += v.x; s.y += v.y; s.z += v.z; s.w += v.w;
    }
    *(float4*)(xb + i) = s;
}

// ---------------------------------------------------------------------------
// Kernel 2: chunked scan (round-6 proven, UNCHANGED)
// ---------------------------------------------------------------------------
__global__ __launch_bounds__(64) void k_scan(const float* __restrict__ xb,
                                             const float* __restrict__ A,
                                             float* __restrict__ hs) {
    const int tid = threadIdx.x;           // 0..63
    const int n = tid & 15;
    const int base4 = (tid & 48) * 4;

    const int chain = blockIdx.x * 4 + (tid >> 4);   // 0..1023
    const int b = chain >> 7;
    const int chunk = chain & 127;
    const int t0 = chunk * CHUNK_L - WARM;

    float Ar[16];
#pragma unroll
    for (int m4 = 0; m4 < 16; m4 += 4) {
        float4 v = *(const float4*)(A + n * 16 + m4);
        Ar[m4 + 0] = v.x; Ar[m4 + 1] = v.y; Ar[m4 + 2] = v.z; Ar[m4 + 3] = v.w;
    }

    const float* xp = xb + (size_t)b * S_DIM * N_DIM + n;
    float* hp = hs + (size_t)b * S_DIM * N_DIM + n;

    float ring[8];
#pragma unroll
    for (int i = 0; i < 8; ++i) {
        int tt = t0 + i;
        ring[i] = (tt >= 0) ? xp[(size_t)tt * N_DIM] : 0.f;
    }

    float h = 0.f;
    for (int tr0 = 0; tr0 < STEPS; tr0 += 8) {
#pragma unroll
        for (int j = 0; j < 8; ++j) {
            const int tr = tr0 + j;
            const float xv = ring[j];
            const int hbits = __float_as_int(h);
            int hm[16];
#pragma unroll
            for (int m = 0; m < 16; ++m)
                hm[m] = __builtin_amdgcn_ds_bpermute(base4 + m * 4, hbits);
            float acc0 = xv, acc1 = 0.f;
#pragma unroll
            for (int m = 0; m < 8; ++m) {
                acc0 = fmaf(Ar[m], __int_as_float(hm[m]), acc0);
                acc1 = fmaf(Ar[m + 8], __int_as_float(hm[m + 8]), acc1);
            }
            float g = acc0 + acc1;
            float ax = fabsf(g);
            float e = __expf(2.f * ax);
            float tv = 1.f - 2.f / (e + 1.f);
            h = (g < 0.f) ? -tv : tv;
            if (tr >= WARM)
                hp[(size_t)(t0 + tr) * N_DIM] = h;
            int tt = t0 + tr + 8;
            if (tr + 8 < STEPS)
                ring[j] = (tt >= 0) ? xp[(size_t)tt * N_DIM] : 0.f;
        }
    }
}

// ---------------------------------------------------------------------------
// Kernel 3: out[r][d] = sum_n hs[r][n] * CW[n][d] + bias[d]  (round-1 proven)
// ---------------------------------------------------------------------------
__global__ __launch_bounds__(256) void k_out(const float* __restrict__ hs,
                                             const float* __restrict__ CW,
                                             const float* __restrict__ bias,
                                             float* __restrict__ out) {
    const int t = threadIdx.x;
    const int d0 = t * 4;
    const int row0 = blockIdx.x * 32;
    float4 cw[16];
#pragma unroll
    for (int nn = 0; nn < 16; ++nn)
        cw[nn] = *(const float4*)(CW + nn * D_DIM + d0);
    float4 b4 = *(const float4*)(bias + d0);

    for (int r = row0; r < row0 + 32; ++r) {
        const float4* hp = (const float4*)(hs + (size_t)r * N_DIM);
        float4 h0 = hp[0], h1 = hp[1], h2 = hp[2], h3 = hp[3];
        float hv[16] = {h0.x, h0.y, h0.z, h0.w, h1.x, h1.y, h1.z, h1.w,
                        h2.x, h2.y, h2.z, h2.w, h3.x, h3.y, h3.z, h3.w};
        float4 acc = b4;
#pragma unroll
        for (int nn = 0; nn < 16; ++nn) {
            acc.x = fmaf(hv[nn], cw[nn].x, acc.x);
            acc.y = fmaf(hv[nn], cw[nn].y, acc.y);
            acc.z = fmaf(hv[nn], cw[nn].z, acc.z);
            acc.w = fmaf(hv[nn], cw[nn].w, acc.w);
        }
        *(float4*)(out + (size_t)r * D_DIM + d0) = acc;
    }
}

// ---------------------------------------------------------------------------
extern "C" void kernel_launch(void* const* d_in, const int* in_sizes, int n_in,
                              void* d_out, int out_size, void* d_ws,
                              size_t ws_size, hipStream_t stream) {
    const float* x    = (const float*)d_in[0];   // [8,4096,1024]
    const float* A    = (const float*)d_in[1];   // [16,16]
    const float* Bm   = (const float*)d_in[2];   // [1024,16]
    const float* C    = (const float*)d_in[3];   // [16,1024]
    const float* W    = (const float*)d_in[4];   // [1024,1024]
    const float* bias = (const float*)d_in[5];   // [1024]
    float* out = (float*)d_out;

    float* ws    = (float*)d_ws;
    float* xb    = ws;                           // 524288 floats
    float* hs    = ws + 524288;                  // 524288
    float* CW    = ws + 1048576;                 // 16384
    float* parts = ws + 1064960;                 // 16 * 524288 floats

    k_xbcw<<<dim3(XB_BLOCKS + CW_BLOCKS), dim3(256), 0, stream>>>(
        x, Bm, parts, C, W, CW);
    k_red<<<dim3(ROWS * N_DIM / 1024), dim3(256), 0, stream>>>(parts, xb);
    k_scan<<<dim3(NCHAIN / 4), dim3(64), 0, stream>>>(xb, A, hs);
    k_out<<<dim3(ROWS / 32), dim3(256), 0, stream>>>(hs, CW, bias, out);
}

// Round 12
// 121.537 us; speedup vs baseline: 3.1922x; 1.4236x over previous
//
#include <hip/hip_runtime.h>
#include <math.h>

#define B_DIM 8
#define S_DIM 4096
#define D_DIM 1024
#define N_DIM 16
#define ROWS (B_DIM * S_DIM)          // 32768

#define CHUNK_L 32
#define WARM 64
#define STEPS (CHUNK_L + WARM)        // 96 sequential steps per chain
#define NCHAIN (B_DIM * (S_DIM / CHUNK_L))   // 1024 chains

#define XR 64                          // rows per xb block
#define XB_BLOCKS (ROWS / XR)          // 512
#define CW_BLOCKS ((N_DIM * D_DIM) / 256)   // 64

// global -> LDS direct DMA, 16B per lane; dest = uniform base + lane*16 (HW).
__device__ __forceinline__ void gl_lds16(const float* g, float* l) {
    __builtin_amdgcn_global_load_lds(
        (const __attribute__((address_space(1))) void*)g,
        (__attribute__((address_space(3))) void*)l, 16, 0, 0);
}

// ---------------------------------------------------------------------------
// Kernel 1 (fused):
//  blocks [0, XB_BLOCKS): xb[r][n] = sum_k x[r][k]*B[k][n], full D per block.
//  m97-style 2-phase: 64x64 x-tile + 64x16 B-tile double-buffered in LDS,
//  staged via global_load_lds width=16 (NO VGPR round-trip -> loads stay in
//  flight on vmcnt; fixes R8-R11's compiler-shredded prefetch, 940cy/load).
//  x source is PRE-SWIZZLED (kb ^= row&7, T2/rule#21) so the linear-dest DMA
//  plus swizzled ds_read_b128 is bank-spread (2 words/bank). B reads are
//  4-address broadcasts (conflict-free). Thread owns 1 row x 4 n; k order
//  ascending -> bit-identical summation to round 1 (absmax 0.0625).
//  blocks [XB_BLOCKS, +CW_BLOCKS): CW[n][d] = sum_k C[n][k]*W[d][k].
// ---------------------------------------------------------------------------
__global__ __launch_bounds__(256) void k_xbcw(const float* __restrict__ x,
                                              const float* __restrict__ Bm,
                                              float* __restrict__ xb,
                                              const float* __restrict__ C,
                                              const float* __restrict__ W,
                                              float* __restrict__ CW) {
    const int t = threadIdx.x;
    if (blockIdx.x >= XB_BLOCKS) {
        // ---- CW part (round-1 proven) ----
        int u = (blockIdx.x - XB_BLOCKS) * 256 + t;
        int d = u >> 4;
        int n = u & 15;
        const float* crow = C + n * D_DIM;
        const float* wrow = W + (size_t)d * D_DIM;
        float acc = 0.f;
#pragma unroll 4
        for (int k = 0; k < D_DIM; k += 4) {
            float4 c4 = *(const float4*)(crow + k);
            float4 w4 = *(const float4*)(wrow + k);
            acc = fmaf(c4.x, w4.x, acc);
            acc = fmaf(c4.y, w4.y, acc);
            acc = fmaf(c4.z, w4.z, acc);
            acc = fmaf(c4.w, w4.w, acc);
        }
        CW[n * D_DIM + d] = acc;
        return;
    }
    // ---- xb tile ----
    __shared__ float xs[2][XR * 64];       // 2 x 16 KB
    __shared__ float bsb[2][64 * N_DIM];   // 2 x 4 KB
    const int w = t >> 6;                  // wave 0..3 (uniform per wave)
    const int l = t & 63;
    const int lr = l >> 4;                 // row-within-issue 0..3
    const int kb = l & 15;                 // 16B k-block 0..15
    const int row0 = blockIdx.x * XR;

    const int row = t >> 2;                // compute: 0..63
    const int nq = (t & 3) * 4;
    const int sw = row & 7;
    float4 acc = {0.f, 0.f, 0.f, 0.f};

#define STAGE(XSB, BSP, KT)                                                 \
    {                                                                       \
        _Pragma("unroll")                                                   \
        for (int i = 0; i < 4; ++i) {                                       \
            int rr = w * 16 + i * 4 + lr;                                   \
            const float* src = x + (size_t)(row0 + rr) * D_DIM +            \
                               (KT) * 64 + ((kb ^ (rr & 7)) * 4);           \
            gl_lds16(src, (XSB) + (w * 16 + i * 4) * 64);                   \
        }                                                                   \
        const float* bsrc = Bm + (size_t)(KT) * 64 * N_DIM + w * 256 + l * 4;\
        gl_lds16(bsrc, (BSP) + w * 256);                                    \
    }

    int cur = 0;
    STAGE(xs[0], bsb[0], 0)
    __syncthreads();                       // drains vmcnt -> tile 0 ready

    for (int kt = 0; kt < 16; ++kt) {
        if (kt < 15) {
            float* xn = xs[cur ^ 1];
            float* bn = bsb[cur ^ 1];
            STAGE(xn, bn, kt + 1)
        }
        const float* xsb = xs[cur];
        const float* bsp = bsb[cur];
#pragma unroll
        for (int q = 0; q < 16; ++q) {
            float4 xv = *(const float4*)(xsb + row * 64 + ((q ^ sw) * 4));
            const float* bk = bsp + q * 4 * N_DIM + nq;
            float4 b0 = *(const float4*)(bk + 0 * N_DIM);
            float4 b1 = *(const float4*)(bk + 1 * N_DIM);
            float4 b2 = *(const float4*)(bk + 2 * N_DIM);
            float4 b3 = *(const float4*)(bk + 3 * N_DIM);
            acc.x = fmaf(xv.x, b0.x, acc.x); acc.y = fmaf(xv.x, b0.y, acc.y);
            acc.z = fmaf(xv.x, b0.z, acc.z); acc.w = fmaf(xv.x, b0.w, acc.w);
            acc.x = fmaf(xv.y, b1.x, acc.x); acc.y = fmaf(xv.y, b1.y, acc.y);
            acc.z = fmaf(xv.y, b1.z, acc.z); acc.w = fmaf(xv.y, b1.w, acc.w);
            acc.x = fmaf(xv.z, b2.x, acc.x); acc.y = fmaf(xv.z, b2.y, acc.y);
            acc.z = fmaf(xv.z, b2.z, acc.z); acc.w = fmaf(xv.z, b2.w, acc.w);
            acc.x = fmaf(xv.w, b3.x, acc.x); acc.y = fmaf(xv.w, b3.y, acc.y);
            acc.z = fmaf(xv.w, b3.z, acc.z); acc.w = fmaf(xv.w, b3.w, acc.w);
        }
        __syncthreads();                   // reads done + next tile drained
        cur ^= 1;
    }
#undef STAGE

    *(float4*)(xb + (size_t)(row0 + row) * N_DIM + nq) = acc;
}

// ---------------------------------------------------------------------------
// Kernel 2: chunked scan (round-6 proven, UNCHANGED)
// ---------------------------------------------------------------------------
__global__ __launch_bounds__(64) void k_scan(const float* __restrict__ xb,
                                             const float* __restrict__ A,
                                             float* __restrict__ hs) {
    const int tid = threadIdx.x;           // 0..63
    const int n = tid & 15;
    const int base4 = (tid & 48) * 4;

    const int chain = blockIdx.x * 4 + (tid >> 4);   // 0..1023
    const int b = chain >> 7;
    const int chunk = chain & 127;
    const int t0 = chunk * CHUNK_L - WARM;

    float Ar[16];
#pragma unroll
    for (int m4 = 0; m4 < 16; m4 += 4) {
        float4 v = *(const float4*)(A + n * 16 + m4);
        Ar[m4 + 0] = v.x; Ar[m4 + 1] = v.y; Ar[m4 + 2] = v.z; Ar[m4 + 3] = v.w;
    }

    const float* xp = xb + (size_t)b * S_DIM * N_DIM + n;
    float* hp = hs + (size_t)b * S_DIM * N_DIM + n;

    float ring[8];
#pragma unroll
    for (int i = 0; i < 8; ++i) {
        int tt = t0 + i;
        ring[i] = (tt >= 0) ? xp[(size_t)tt * N_DIM] : 0.f;
    }

    float h = 0.f;
    for (int tr0 = 0; tr0 < STEPS; tr0 += 8) {
#pragma unroll
        for (int j = 0; j < 8; ++j) {
            const int tr = tr0 + j;
            const float xv = ring[j];
            const int hbits = __float_as_int(h);
            int hm[16];
#pragma unroll
            for (int m = 0; m < 16; ++m)
                hm[m] = __builtin_amdgcn_ds_bpermute(base4 + m * 4, hbits);
            float acc0 = xv, acc1 = 0.f;
#pragma unroll
            for (int m = 0; m < 8; ++m) {
                acc0 = fmaf(Ar[m], __int_as_float(hm[m]), acc0);
                acc1 = fmaf(Ar[m + 8], __int_as_float(hm[m + 8]), acc1);
            }
            float g = acc0 + acc1;
            float ax = fabsf(g);
            float e = __expf(2.f * ax);
            float tv = 1.f - 2.f / (e + 1.f);
            h = (g < 0.f) ? -tv : tv;
            if (tr >= WARM)
                hp[(size_t)(t0 + tr) * N_DIM] = h;
            int tt = t0 + tr + 8;
            if (tr + 8 < STEPS)
                ring[j] = (tt >= 0) ? xp[(size_t)tt * N_DIM] : 0.f;
        }
    }
}

// ---------------------------------------------------------------------------
// Kernel 3: out[r][d] = sum_n hs[r][n] * CW[n][d] + bias[d]  (round-1 proven)
// ---------------------------------------------------------------------------
__global__ __launch_bounds__(256) void k_out(const float* __restrict__ hs,
                                             const float* __restrict__ CW,
                                             const float* __restrict__ bias,
                                             float* __restrict__ out) {
    const int t = threadIdx.x;
    const int d0 = t * 4;
    const int row0 = blockIdx.x * 32;
    float4 cw[16];
#pragma unroll
    for (int nn = 0; nn < 16; ++nn)
        cw[nn] = *(const float4*)(CW + nn * D_DIM + d0);
    float4 b4 = *(const float4*)(bias + d0);

    for (int r = row0; r < row0 + 32; ++r) {
        const float4* hp = (const float4*)(hs + (size_t)r * N_DIM);
        float4 h0 = hp[0], h1 = hp[1], h2 = hp[2], h3 = hp[3];
        float hv[16] = {h0.x, h0.y, h0.z, h0.w, h1.x, h1.y, h1.z, h1.w,
                        h2.x, h2.y, h2.z, h2.w, h3.x, h3.y, h3.z, h3.w};
        float4 acc = b4;
#pragma unroll
        for (int nn = 0; nn < 16; ++nn) {
            acc.x = fmaf(hv[nn], cw[nn].x, acc.x);
            acc.y = fmaf(hv[nn], cw[nn].y, acc.y);
            acc.z = fmaf(hv[nn], cw[nn].z, acc.z);
            acc.w = fmaf(hv[nn], cw[nn].w, acc.w);
        }
        *(float4*)(out + (size_t)r * D_DIM + d0) = acc;
    }
}

// ---------------------------------------------------------------------------
extern "C" void kernel_launch(void* const* d_in, const int* in_sizes, int n_in,
                              void* d_out, int out_size, void* d_ws,
                              size_t ws_size, hipStream_t stream) {
    const float* x    = (const float*)d_in[0];   // [8,4096,1024]
    const float* A    = (const float*)d_in[1];   // [16,16]
    const float* Bm   = (const float*)d_in[2];   // [1024,16]
    const float* C    = (const float*)d_in[3];   // [16,1024]
    const float* W    = (const float*)d_in[4];   // [1024,1024]
    const float* bias = (const float*)d_in[5];   // [1024]
    float* out = (float*)d_out;

    float* ws = (float*)d_ws;
    float* xb = ws;                            // 524288 floats
    float* hs = ws + 524288;                   // 524288
    float* CW = ws + 1048576;                  // 16384

    k_xbcw<<<dim3(XB_BLOCKS + CW_BLOCKS), dim3(256), 0, stream>>>(
        x, Bm, xb, C, W, CW);
    k_scan<<<dim3(NCHAIN / 4), dim3(64), 0, stream>>>(xb, A, hs);
    k_out<<<dim3(ROWS / 32), dim3(256), 0, stream>>>(hs, CW, bias, out);
}